// Round 2
// baseline (2736.164 us; speedup 1.0000x reference)
//
#include <hip/hip_runtime.h>
#include <hip/hip_bf16.h>

// GINE backbone, 3 layers, fp32. N=50000 nodes, E=500000 edges, IN=27, ED=12, H=128.
//
// Per layer:
//   agg = (1+eps)*x                                  (init_agg)
//   agg[dst] += relu(x[src] + ea@eW + eb)            (edge_kernel, atomics)
//   h1 = agg@W1 + b1                                 (gemm<false>)
//   stats(h1) -> scale1/shift1                       (col_stats + finalize_bn)
//   h2 = relu(h1*scale1+shift1)@W2 + b2              (gemm<true>, BN+ReLU fused in A-load)
//   stats(h2) -> scale2/shift2
//   x_next = [xprev + 0.3*] relu(h2*scale2+shift2)   (bn_apply)

static inline int cdiv(int a, int b) { return (a + b - 1) / b; }

// ---------------------------------------------------------------- init agg
__global__ __launch_bounds__(256) void init_agg(const float* __restrict__ x,
                                                const float* __restrict__ epsp,
                                                float* __restrict__ agg, int total) {
    float s = 1.0f + *epsp;
    int i = blockIdx.x * blockDim.x + threadIdx.x;
    int stride = gridDim.x * blockDim.x;
    for (; i < total; i += stride) agg[i] = s * x[i];
}

// ---------------------------------------------------------------- edge kernel
// 32 lanes per edge. ea row (12 floats) loaded by lanes 0-11, broadcast via shfl.
// IND=27: 1 dim/lane (d<27 guard). IND=128: 4 dims/lane (float4).
template <int IND>
__global__ __launch_bounds__(256) void edge_kernel(const int* __restrict__ src,
                                                   const int* __restrict__ dst,
                                                   const float* __restrict__ ea,
                                                   const float* __restrict__ eW,
                                                   const float* __restrict__ eb,
                                                   const float* __restrict__ x,
                                                   float* __restrict__ agg, int E) {
    __shared__ __align__(16) float sW[12 * IND];
    __shared__ __align__(16) float sb[IND];
    int tid = threadIdx.x;
    for (int i = tid; i < 12 * IND; i += 256) sW[i] = eW[i];
    for (int i = tid; i < IND; i += 256) sb[i] = eb[i];
    __syncthreads();

    int lane = tid & 31;
    int esub = tid >> 5;  // 8 edges per block-iteration
    for (int e = blockIdx.x * 8 + esub; e < E; e += gridDim.x * 8) {
        int s = src[e];
        int t = dst[e];
        float av = (lane < 12) ? ea[(size_t)e * 12 + lane] : 0.0f;

        if constexpr (IND == 128) {
            int d0 = lane << 2;
            float4 acc = *(const float4*)&sb[d0];
#pragma unroll
            for (int k = 0; k < 12; ++k) {
                float ak = __shfl(av, k, 32);
                float4 w = *(const float4*)&sW[k * 128 + d0];
                acc.x = fmaf(ak, w.x, acc.x);
                acc.y = fmaf(ak, w.y, acc.y);
                acc.z = fmaf(ak, w.z, acc.z);
                acc.w = fmaf(ak, w.w, acc.w);
            }
            float4 xv = *(const float4*)&x[(size_t)s * 128 + d0];
            float m0 = fmaxf(xv.x + acc.x, 0.0f);
            float m1 = fmaxf(xv.y + acc.y, 0.0f);
            float m2 = fmaxf(xv.z + acc.z, 0.0f);
            float m3 = fmaxf(xv.w + acc.w, 0.0f);
            float* ap = &agg[(size_t)t * 128 + d0];
            atomicAdd(ap + 0, m0);
            atomicAdd(ap + 1, m1);
            atomicAdd(ap + 2, m2);
            atomicAdd(ap + 3, m3);
        } else {
            int d = lane;
            if (d < IND) {
                float acc = sb[d];
#pragma unroll
                for (int k = 0; k < 12; ++k) {
                    float ak = __shfl(av, k, 32);
                    acc = fmaf(ak, sW[k * IND + d], acc);
                }
                float m = fmaxf(x[(size_t)s * IND + d] + acc, 0.0f);
                atomicAdd(&agg[(size_t)t * IND + d], m);
            }
        }
    }
}

// ---------------------------------------------------------------- fp32 GEMM
// C[M,·] = pre(A[M,K]) @ B[K,·] + bias.  128x64 tile, 256 thr, 8x4/thread, BK=32.
// PRE_BN: a' = relu(a*scale[k] + shift[k]) applied on A-load.
template <bool PRE_BN>
__global__ __launch_bounds__(256) void gemm_kernel(const float* __restrict__ A, int M, int K,
                                                   int lda, const float* __restrict__ B, int ldb,
                                                   const float* __restrict__ bias,
                                                   const float* __restrict__ scale,
                                                   const float* __restrict__ shift,
                                                   float* __restrict__ C, int ldc) {
    __shared__ __align__(16) float As[32][132];  // [k][m], 528B rows (16B-aligned)
    __shared__ __align__(16) float Bs[32][68];   // [k][n], 272B rows
    int row0 = blockIdx.x * 128;
    int col0 = blockIdx.y * 64;
    int tid = threadIdx.x;
    int tm = tid >> 4, tn = tid & 15;
    int m0 = tm << 3, n0 = tn << 2;

    float acc[8][4] = {};

    for (int k0 = 0; k0 < K; k0 += 32) {
        int kt = K - k0;
        if (kt > 32) kt = 32;
        // load A tile (128 x kt), zero-pad rest. 16 elems/thread.
        for (int idx = tid; idx < 128 * 32; idx += 256) {
            int m = idx >> 5, k = idx & 31;
            float v = 0.0f;
            int gm = row0 + m;
            if (k < kt && gm < M) {
                v = A[(size_t)gm * lda + k0 + k];
                if (PRE_BN) v = fmaxf(fmaf(v, scale[k0 + k], shift[k0 + k]), 0.0f);
            }
            As[k][m] = v;
        }
        // load B tile (kt x 64), zero-pad rest. 8 elems/thread.
        for (int idx = tid; idx < 32 * 64; idx += 256) {
            int k = idx >> 6, n = idx & 63;
            float v = 0.0f;
            if (k < kt) v = B[(size_t)(k0 + k) * ldb + col0 + n];
            Bs[k][n] = v;
        }
        __syncthreads();
#pragma unroll
        for (int k = 0; k < 32; ++k) {
            float4 a0 = *(const float4*)&As[k][m0];
            float4 a1 = *(const float4*)&As[k][m0 + 4];
            float4 bv = *(const float4*)&Bs[k][n0];
            float am[8] = {a0.x, a0.y, a0.z, a0.w, a1.x, a1.y, a1.z, a1.w};
#pragma unroll
            for (int i = 0; i < 8; ++i) {
                acc[i][0] = fmaf(am[i], bv.x, acc[i][0]);
                acc[i][1] = fmaf(am[i], bv.y, acc[i][1]);
                acc[i][2] = fmaf(am[i], bv.z, acc[i][2]);
                acc[i][3] = fmaf(am[i], bv.w, acc[i][3]);
            }
        }
        __syncthreads();
    }

    float b0 = bias[col0 + n0 + 0];
    float b1 = bias[col0 + n0 + 1];
    float b2 = bias[col0 + n0 + 2];
    float b3 = bias[col0 + n0 + 3];
#pragma unroll
    for (int i = 0; i < 8; ++i) {
        int row = row0 + m0 + i;
        if (row < M) {
            float4 o;
            o.x = acc[i][0] + b0;
            o.y = acc[i][1] + b1;
            o.z = acc[i][2] + b2;
            o.w = acc[i][3] + b3;
            *(float4*)&C[(size_t)row * ldc + col0 + n0] = o;
        }
    }
}

// ---------------------------------------------------------------- column stats
__global__ __launch_bounds__(256) void col_stats(const float* __restrict__ A, int M, int C,
                                                 float* __restrict__ sums,
                                                 float* __restrict__ sumsq) {
    int tid = threadIdx.x;
    int col = tid % C;
    int rsub = tid / C;
    int rstride = 256 / C;
    int r0 = blockIdx.x * 256;
    int rend = r0 + 256;
    if (rend > M) rend = M;
    float s = 0.0f, q = 0.0f;
    for (int r = r0 + rsub; r < rend; r += rstride) {
        float v = A[(size_t)r * C + col];
        s += v;
        q = fmaf(v, v, q);
    }
    atomicAdd(&sums[col], s);
    atomicAdd(&sumsq[col], q);
}

__global__ void finalize_bn(const float* __restrict__ sums, const float* __restrict__ sumsq,
                            const float* __restrict__ g, const float* __restrict__ b,
                            float* __restrict__ scale, float* __restrict__ shift, int C,
                            float invN) {
    int c = blockIdx.x * blockDim.x + threadIdx.x;
    if (c < C) {
        float mu = sums[c] * invN;
        float var = sumsq[c] * invN - mu * mu;
        float inv = rsqrtf(var + 1e-5f);
        float sc = g[c] * inv;
        scale[c] = sc;
        shift[c] = b[c] - mu * sc;
    }
}

// ---------------------------------------------------------------- BN apply (+residual)
template <bool RES>
__global__ __launch_bounds__(256) void bn_apply(const float* __restrict__ h,
                                                const float* __restrict__ scale,
                                                const float* __restrict__ shift,
                                                const float* __restrict__ xprev,
                                                float* __restrict__ out, int total4) {
    int i = blockIdx.x * blockDim.x + threadIdx.x;
    int stride = gridDim.x * blockDim.x;
    for (; i < total4; i += stride) {
        int c0 = (i & 31) << 2;  // column = (4*i) % 128
        float4 v = ((const float4*)h)[i];
        float4 o;
        o.x = fmaxf(fmaf(v.x, scale[c0 + 0], shift[c0 + 0]), 0.0f);
        o.y = fmaxf(fmaf(v.y, scale[c0 + 1], shift[c0 + 1]), 0.0f);
        o.z = fmaxf(fmaf(v.z, scale[c0 + 2], shift[c0 + 2]), 0.0f);
        o.w = fmaxf(fmaf(v.w, scale[c0 + 3], shift[c0 + 3]), 0.0f);
        if (RES) {
            float4 xp = ((const float4*)xprev)[i];
            o.x = fmaf(0.3f, o.x, xp.x);
            o.y = fmaf(0.3f, o.y, xp.y);
            o.z = fmaf(0.3f, o.z, xp.z);
            o.w = fmaf(0.3f, o.w, xp.w);
        }
        ((float4*)out)[i] = o;
    }
}

// ---------------------------------------------------------------- launch
extern "C" void kernel_launch(void* const* d_in, const int* in_sizes, int n_in, void* d_out,
                              int out_size, void* d_ws, size_t ws_size, hipStream_t stream) {
    const float* x_in = (const float*)d_in[0];
    const int* ei = (const int*)d_in[1];
    const float* ea = (const float*)d_in[2];
    const int IN_DIM = 27;
    const int H = 128;
    int N = in_sizes[0] / IN_DIM;
    int E = in_sizes[1] / 2;
    const int* src = ei;
    const int* dst = ei + E;

    auto L = [&](int layer, int j) -> const float* {
        return (const float*)d_in[3 + 11 * layer + j];
    };
    // j: 0 eps, 1 eW, 2 eb, 3 W1, 4 b1, 5 g1, 6 be1, 7 W2, 8 b2, 9 ng, 10 nb

    float* X0 = (float*)d_ws;                 // [N,128]
    float* X1 = X0 + (size_t)N * H;           // [N,128]
    float* AGG = X1 + (size_t)N * H;          // [N,128]  (also h2)
    float* H1 = AGG + (size_t)N * H;          // [N,256]
    float* STATS = H1 + (size_t)N * 2 * H;
    float* sums1 = STATS;          // 256
    float* sq1 = STATS + 256;      // 256
    float* sums2 = STATS + 512;    // 128
    float* sq2 = STATS + 640;      // 128
    float* scale1 = STATS + 768;   // 256
    float* shift1 = STATS + 1024;  // 256
    float* scale2 = STATS + 1280;  // 128
    float* shift2 = STATS + 1408;  // 128

    float invN = 1.0f / (float)N;
    int gridM = cdiv(N, 128);
    int statG = cdiv(N, 256);

    for (int i = 0; i < 3; ++i) {
        int ind = (i == 0) ? IN_DIM : H;
        const float* xin = (i == 0) ? x_in : ((i == 1) ? X0 : X1);
        float* xout = (i == 2) ? (float*)d_out : ((i == 0) ? X0 : X1);

        hipMemsetAsync(STATS, 0, 768 * sizeof(float), stream);

        int totalA = N * ind;
        init_agg<<<1024, 256, 0, stream>>>(xin, L(i, 0), AGG, totalA);

        int eg = min(2048, cdiv(E, 8));
        if (i == 0)
            edge_kernel<27><<<eg, 256, 0, stream>>>(src, dst, ea, L(i, 1), L(i, 2), xin, AGG, E);
        else
            edge_kernel<128><<<eg, 256, 0, stream>>>(src, dst, ea, L(i, 1), L(i, 2), xin, AGG, E);

        // h1 = agg @ W1 + b1   [N, 256]
        gemm_kernel<false><<<dim3(gridM, 4), 256, 0, stream>>>(AGG, N, ind, ind, L(i, 3), 256,
                                                               L(i, 4), nullptr, nullptr, H1, 256);
        col_stats<<<statG, 256, 0, stream>>>(H1, N, 256, sums1, sq1);
        finalize_bn<<<1, 256, 0, stream>>>(sums1, sq1, L(i, 5), L(i, 6), scale1, shift1, 256, invN);

        // h2 = relu(bn1(h1)) @ W2 + b2   [N, 128]
        gemm_kernel<true><<<dim3(gridM, 2), 256, 0, stream>>>(H1, N, 256, 256, L(i, 7), 128,
                                                              L(i, 8), scale1, shift1, AGG, 128);
        col_stats<<<statG, 256, 0, stream>>>(AGG, N, 128, sums2, sq2);
        finalize_bn<<<1, 256, 0, stream>>>(sums2, sq2, L(i, 9), L(i, 10), scale2, shift2, 128,
                                           invN);

        int total4 = N * H / 4;
        if (i == 1)
            bn_apply<true><<<2048, 256, 0, stream>>>(AGG, scale2, shift2, X0, xout, total4);
        else
            bn_apply<false><<<2048, 256, 0, stream>>>(AGG, scale2, shift2, nullptr, xout, total4);
    }
}

// Round 3
// 1332.601 us; speedup vs baseline: 2.0533x; 2.0533x over previous
//
#include <hip/hip_runtime.h>
#include <hip/hip_bf16.h>

// GINE backbone, 3 layers, fp32. N=50000 nodes, E=500000 edges, IN=27, ED=12, H=128.
//
// Round 2 -> 3 change: edge aggregation rebuilt as on-device CSR + per-node
// gather (no fp32 atomics). CSR built once per launch, reused by all 3 layers.
//
// Per layer:
//   agg[n] = (1+eps)*x[n] + sum_{e: dst=n} relu(x[src] + ea@eW + eb)   (gather)
//   h1 = agg@W1 + b1                                 (gemm<false>)
//   stats(h1) -> scale1/shift1                       (col_stats + finalize_bn)
//   h2 = relu(h1*scale1+shift1)@W2 + b2              (gemm<true>, BN+ReLU fused in A-load)
//   stats(h2) -> scale2/shift2
//   x_next = [xprev + 0.3*] relu(h2*scale2+shift2)   (bn_apply)

static inline int cdiv(int a, int b) { return (a + b - 1) / b; }

// ---------------------------------------------------------------- CSR build
__global__ __launch_bounds__(256) void histogram_dst(const int* __restrict__ dst,
                                                     int* __restrict__ deg, int E) {
    int i = blockIdx.x * blockDim.x + threadIdx.x;
    int stride = gridDim.x * blockDim.x;
    for (; i < E; i += stride) atomicAdd(&deg[dst[i]], 1);
}

// single-block exclusive scan: rowptr[0..N] from deg[0..N)
__global__ __launch_bounds__(1024) void scan_deg(const int* __restrict__ deg,
                                                 int* __restrict__ rowptr, int N) {
    __shared__ int part[1024];
    int t = threadIdx.x;
    int chunk = (N + 1023) / 1024;
    int b = t * chunk;
    int e = b + chunk;
    if (b > N) b = N;
    if (e > N) e = N;
    int s = 0;
    for (int i = b; i < e; ++i) s += deg[i];
    part[t] = s;
    __syncthreads();
    for (int off = 1; off < 1024; off <<= 1) {
        int v = (t >= off) ? part[t - off] : 0;
        __syncthreads();
        part[t] += v;
        __syncthreads();
    }
    int base = (t == 0) ? 0 : part[t - 1];
    for (int i = b; i < e; ++i) {
        rowptr[i] = base;
        base += deg[i];
    }
    if (t == 1023) rowptr[N] = base;
}

__global__ __launch_bounds__(256) void scatter_edges(const int* __restrict__ dst,
                                                     int* __restrict__ cursor,
                                                     int* __restrict__ eid, int E) {
    int i = blockIdx.x * blockDim.x + threadIdx.x;
    int stride = gridDim.x * blockDim.x;
    for (; i < E; i += stride) {
        int pos = atomicAdd(&cursor[dst[i]], 1);
        eid[pos] = i;
    }
}

// ---------------------------------------------------------------- gather (edge agg, no atomics)
// One 32-lane group per node. agg[n] = (1+eps)*x[n] + sum relu(x[src] + ea@eW + eb).
// IND=128: 4 dims/lane (float4). IND=27: 1 dim/lane, lanes 27-31 idle.
template <int IND>
__global__ __launch_bounds__(256) void gather_kernel(
    const int* __restrict__ rowptr, const int* __restrict__ eid, const int* __restrict__ src,
    const float* __restrict__ ea, const float* __restrict__ eW, const float* __restrict__ eb,
    const float* __restrict__ x, const float* __restrict__ epsp, float* __restrict__ agg, int N) {
    __shared__ __align__(16) float sW[12 * IND];
    __shared__ __align__(16) float sb[IND];
    int tid = threadIdx.x;
    for (int i = tid; i < 12 * IND; i += 256) sW[i] = eW[i];
    for (int i = tid; i < IND; i += 256) sb[i] = eb[i];
    __syncthreads();

    float onePlusEps = 1.0f + *epsp;
    int lane = tid & 31;
    int n = blockIdx.x * 8 + (tid >> 5);
    if (n >= N) return;
    int beg = rowptr[n], end = rowptr[n + 1];

    if constexpr (IND == 128) {
        int d0 = lane << 2;
        float4 acc = make_float4(0.f, 0.f, 0.f, 0.f);
        float4 bb = *(const float4*)&sb[d0];
        for (int i = beg; i < end; ++i) {
            int e = eid[i];
            int s = src[e];
            float av = (lane < 12) ? ea[(size_t)e * 12 + lane] : 0.0f;
            float4 p = bb;
#pragma unroll
            for (int k = 0; k < 12; ++k) {
                float ak = __shfl(av, k, 32);
                float4 w = *(const float4*)&sW[k * 128 + d0];
                p.x = fmaf(ak, w.x, p.x);
                p.y = fmaf(ak, w.y, p.y);
                p.z = fmaf(ak, w.z, p.z);
                p.w = fmaf(ak, w.w, p.w);
            }
            float4 xv = *(const float4*)&x[(size_t)s * 128 + d0];
            acc.x += fmaxf(xv.x + p.x, 0.0f);
            acc.y += fmaxf(xv.y + p.y, 0.0f);
            acc.z += fmaxf(xv.z + p.z, 0.0f);
            acc.w += fmaxf(xv.w + p.w, 0.0f);
        }
        float4 xn = *(const float4*)&x[(size_t)n * 128 + d0];
        float4 o;
        o.x = fmaf(onePlusEps, xn.x, acc.x);
        o.y = fmaf(onePlusEps, xn.y, acc.y);
        o.z = fmaf(onePlusEps, xn.z, acc.z);
        o.w = fmaf(onePlusEps, xn.w, acc.w);
        *(float4*)&agg[(size_t)n * 128 + d0] = o;
    } else {
        int d = lane;
        float acc = 0.0f;
        float bb = (d < IND) ? sb[d] : 0.0f;
        for (int i = beg; i < end; ++i) {
            int e = eid[i];
            int s = src[e];
            float av = (lane < 12) ? ea[(size_t)e * 12 + lane] : 0.0f;
            float p = bb;
#pragma unroll
            for (int k = 0; k < 12; ++k) {
                float ak = __shfl(av, k, 32);
                if (d < IND) p = fmaf(ak, sW[k * IND + d], p);
            }
            if (d < IND) acc += fmaxf(x[(size_t)s * IND + d] + p, 0.0f);
        }
        if (d < IND) agg[(size_t)n * IND + d] = fmaf(onePlusEps, x[(size_t)n * IND + d], acc);
    }
}

// ---------------------------------------------------------------- fp32 GEMM
// C[M,·] = pre(A[M,K]) @ B[K,·] + bias.  128x64 tile, 256 thr, 8x4/thread, BK=32.
// PRE_BN: a' = relu(a*scale[k] + shift[k]) applied on A-load.
template <bool PRE_BN>
__global__ __launch_bounds__(256) void gemm_kernel(const float* __restrict__ A, int M, int K,
                                                   int lda, const float* __restrict__ B, int ldb,
                                                   const float* __restrict__ bias,
                                                   const float* __restrict__ scale,
                                                   const float* __restrict__ shift,
                                                   float* __restrict__ C, int ldc) {
    __shared__ __align__(16) float As[32][132];  // [k][m], 528B rows (16B-aligned)
    __shared__ __align__(16) float Bs[32][68];   // [k][n], 272B rows
    int row0 = blockIdx.x * 128;
    int col0 = blockIdx.y * 64;
    int tid = threadIdx.x;
    int tm = tid >> 4, tn = tid & 15;
    int m0 = tm << 3, n0 = tn << 2;

    float acc[8][4] = {};

    for (int k0 = 0; k0 < K; k0 += 32) {
        int kt = K - k0;
        if (kt > 32) kt = 32;
        for (int idx = tid; idx < 128 * 32; idx += 256) {
            int m = idx >> 5, k = idx & 31;
            float v = 0.0f;
            int gm = row0 + m;
            if (k < kt && gm < M) {
                v = A[(size_t)gm * lda + k0 + k];
                if (PRE_BN) v = fmaxf(fmaf(v, scale[k0 + k], shift[k0 + k]), 0.0f);
            }
            As[k][m] = v;
        }
        for (int idx = tid; idx < 32 * 64; idx += 256) {
            int k = idx >> 6, n = idx & 63;
            float v = 0.0f;
            if (k < kt) v = B[(size_t)(k0 + k) * ldb + col0 + n];
            Bs[k][n] = v;
        }
        __syncthreads();
#pragma unroll
        for (int k = 0; k < 32; ++k) {
            float4 a0 = *(const float4*)&As[k][m0];
            float4 a1 = *(const float4*)&As[k][m0 + 4];
            float4 bv = *(const float4*)&Bs[k][n0];
            float am[8] = {a0.x, a0.y, a0.z, a0.w, a1.x, a1.y, a1.z, a1.w};
#pragma unroll
            for (int i = 0; i < 8; ++i) {
                acc[i][0] = fmaf(am[i], bv.x, acc[i][0]);
                acc[i][1] = fmaf(am[i], bv.y, acc[i][1]);
                acc[i][2] = fmaf(am[i], bv.z, acc[i][2]);
                acc[i][3] = fmaf(am[i], bv.w, acc[i][3]);
            }
        }
        __syncthreads();
    }

    float b0 = bias[col0 + n0 + 0];
    float b1 = bias[col0 + n0 + 1];
    float b2 = bias[col0 + n0 + 2];
    float b3 = bias[col0 + n0 + 3];
#pragma unroll
    for (int i = 0; i < 8; ++i) {
        int row = row0 + m0 + i;
        if (row < M) {
            float4 o;
            o.x = acc[i][0] + b0;
            o.y = acc[i][1] + b1;
            o.z = acc[i][2] + b2;
            o.w = acc[i][3] + b3;
            *(float4*)&C[(size_t)row * ldc + col0 + n0] = o;
        }
    }
}

// ---------------------------------------------------------------- column stats
__global__ __launch_bounds__(256) void col_stats(const float* __restrict__ A, int M, int C,
                                                 float* __restrict__ sums,
                                                 float* __restrict__ sumsq) {
    int tid = threadIdx.x;
    int col = tid % C;
    int rsub = tid / C;
    int rstride = 256 / C;
    int r0 = blockIdx.x * 256;
    int rend = r0 + 256;
    if (rend > M) rend = M;
    float s = 0.0f, q = 0.0f;
    for (int r = r0 + rsub; r < rend; r += rstride) {
        float v = A[(size_t)r * C + col];
        s += v;
        q = fmaf(v, v, q);
    }
    atomicAdd(&sums[col], s);
    atomicAdd(&sumsq[col], q);
}

__global__ void finalize_bn(const float* __restrict__ sums, const float* __restrict__ sumsq,
                            const float* __restrict__ g, const float* __restrict__ b,
                            float* __restrict__ scale, float* __restrict__ shift, int C,
                            float invN) {
    int c = blockIdx.x * blockDim.x + threadIdx.x;
    if (c < C) {
        float mu = sums[c] * invN;
        float var = sumsq[c] * invN - mu * mu;
        float inv = rsqrtf(var + 1e-5f);
        float sc = g[c] * inv;
        scale[c] = sc;
        shift[c] = b[c] - mu * sc;
    }
}

// ---------------------------------------------------------------- BN apply (+residual)
template <bool RES>
__global__ __launch_bounds__(256) void bn_apply(const float* __restrict__ h,
                                                const float* __restrict__ scale,
                                                const float* __restrict__ shift,
                                                const float* __restrict__ xprev,
                                                float* __restrict__ out, int total4) {
    int i = blockIdx.x * blockDim.x + threadIdx.x;
    int stride = gridDim.x * blockDim.x;
    for (; i < total4; i += stride) {
        int c0 = (i & 31) << 2;  // column = (4*i) % 128
        float4 v = ((const float4*)h)[i];
        float4 o;
        o.x = fmaxf(fmaf(v.x, scale[c0 + 0], shift[c0 + 0]), 0.0f);
        o.y = fmaxf(fmaf(v.y, scale[c0 + 1], shift[c0 + 1]), 0.0f);
        o.z = fmaxf(fmaf(v.z, scale[c0 + 2], shift[c0 + 2]), 0.0f);
        o.w = fmaxf(fmaf(v.w, scale[c0 + 3], shift[c0 + 3]), 0.0f);
        if (RES) {
            float4 xp = ((const float4*)xprev)[i];
            o.x = fmaf(0.3f, o.x, xp.x);
            o.y = fmaf(0.3f, o.y, xp.y);
            o.z = fmaf(0.3f, o.z, xp.z);
            o.w = fmaf(0.3f, o.w, xp.w);
        }
        ((float4*)out)[i] = o;
    }
}

// ---------------------------------------------------------------- launch
extern "C" void kernel_launch(void* const* d_in, const int* in_sizes, int n_in, void* d_out,
                              int out_size, void* d_ws, size_t ws_size, hipStream_t stream) {
    const float* x_in = (const float*)d_in[0];
    const int* ei = (const int*)d_in[1];
    const float* ea = (const float*)d_in[2];
    const int IN_DIM = 27;
    const int H = 128;
    int N = in_sizes[0] / IN_DIM;
    int E = in_sizes[1] / 2;
    const int* src = ei;
    const int* dst = ei + E;

    auto L = [&](int layer, int j) -> const float* {
        return (const float*)d_in[3 + 11 * layer + j];
    };
    // j: 0 eps, 1 eW, 2 eb, 3 W1, 4 b1, 5 g1, 6 be1, 7 W2, 8 b2, 9 ng, 10 nb

    // ws layout (floats): X0[N*128] AGG[N*128] H1[N*256] STATS[1536] | ints: rowptr[N+1] cursor[N] eid[E]
    float* X0 = (float*)d_ws;        // [N,128]
    float* AGG = X0 + (size_t)N * H; // [N,128]  (also h2)
    float* H1 = AGG + (size_t)N * H; // [N,256]
    float* STATS = H1 + (size_t)N * 2 * H;
    float* sums1 = STATS;
    float* sq1 = STATS + 256;
    float* sums2 = STATS + 512;
    float* sq2 = STATS + 640;
    float* scale1 = STATS + 768;
    float* shift1 = STATS + 1024;
    float* scale2 = STATS + 1280;
    float* shift2 = STATS + 1408;
    int* rowptr = (int*)(STATS + 1536);  // N+1
    int* cursor = rowptr + (N + 1);      // N
    int* eid = cursor + N;               // E
    float* X1 = (float*)d_out;           // layer-1 output lives in d_out

    float invN = 1.0f / (float)N;
    int gridM = cdiv(N, 128);
    int statG = cdiv(N, 256);
    int gatherG = cdiv(N, 8);

    // ---- CSR build (once; reused by all 3 layers)
    hipMemsetAsync(rowptr, 0, (size_t)(N + 1) * sizeof(int), stream);
    histogram_dst<<<1024, 256, 0, stream>>>(dst, rowptr, E);  // rowptr holds deg
    scan_deg<<<1, 1024, 0, stream>>>(rowptr, cursor, N);      // NOTE: scan reads deg from rowptr
    // cursor now holds exclusive scan in [0..N-1]; move it to rowptr and keep a working copy
    hipMemcpyAsync(rowptr, cursor, (size_t)(N + 1) * sizeof(int), hipMemcpyDeviceToDevice, stream);
    scatter_edges<<<1024, 256, 0, stream>>>(dst, cursor, eid, E);

    for (int i = 0; i < 3; ++i) {
        int ind = (i == 0) ? IN_DIM : H;
        const float* xin = (i == 0) ? x_in : ((i == 1) ? X0 : X1);
        float* xout = (i == 2) ? (float*)d_out : ((i == 0) ? X0 : X1);

        hipMemsetAsync(STATS, 0, 768 * sizeof(float), stream);

        if (i == 0)
            gather_kernel<27><<<gatherG, 256, 0, stream>>>(rowptr, eid, src, ea, L(i, 1), L(i, 2),
                                                           xin, L(i, 0), AGG, N);
        else
            gather_kernel<128><<<gatherG, 256, 0, stream>>>(rowptr, eid, src, ea, L(i, 1), L(i, 2),
                                                            xin, L(i, 0), AGG, N);

        // h1 = agg @ W1 + b1   [N, 256]
        gemm_kernel<false><<<dim3(gridM, 4), 256, 0, stream>>>(AGG, N, ind, ind, L(i, 3), 256,
                                                               L(i, 4), nullptr, nullptr, H1, 256);
        col_stats<<<statG, 256, 0, stream>>>(H1, N, 256, sums1, sq1);
        finalize_bn<<<1, 256, 0, stream>>>(sums1, sq1, L(i, 5), L(i, 6), scale1, shift1, 256, invN);

        // h2 = relu(bn1(h1)) @ W2 + b2   [N, 128]
        gemm_kernel<true><<<dim3(gridM, 2), 256, 0, stream>>>(H1, N, 256, 256, L(i, 7), 128,
                                                              L(i, 8), scale1, shift1, AGG, 128);
        col_stats<<<statG, 256, 0, stream>>>(AGG, N, 128, sums2, sq2);
        finalize_bn<<<1, 256, 0, stream>>>(sums2, sq2, L(i, 9), L(i, 10), scale2, shift2, 128,
                                           invN);

        int total4 = N * H / 4;
        if (i == 1)
            bn_apply<true><<<2048, 256, 0, stream>>>(AGG, scale2, shift2, X0, xout, total4);
        else
            bn_apply<false><<<2048, 256, 0, stream>>>(AGG, scale2, shift2, nullptr, xout, total4);
    }
}

// Round 5
// 967.553 us; speedup vs baseline: 2.8279x; 1.3773x over previous
//
#include <hip/hip_runtime.h>
#include <hip/hip_bf16.h>

// GINE backbone, 3 layers. N=50000, E=500000, IN=27, ED=12, H=128.
// Round 3 -> 4 (resubmit; r4 GPU timeout): GEMMs on MFMA (bf16 hi/lo split,
// fp32-accurate), col_stats fused into GEMM epilogue, gather 2x-unrolled.

typedef __attribute__((ext_vector_type(8))) short bf16x8;
typedef __attribute__((ext_vector_type(4))) float f32x4;

static inline int cdiv(int a, int b) { return (a + b - 1) / b; }

__device__ inline ushort f2bf(float f) {
    uint32_t u = __float_as_uint(f);
    return (ushort)((u + 0x7FFFu + ((u >> 16) & 1u)) >> 16);
}
__device__ inline float bf2f(ushort h) { return __uint_as_float(((uint32_t)h) << 16); }

// ---------------------------------------------------------------- CSR build
__global__ __launch_bounds__(256) void histogram_dst(const int* __restrict__ dst,
                                                     int* __restrict__ deg, int E) {
    int i = blockIdx.x * blockDim.x + threadIdx.x;
    int stride = gridDim.x * blockDim.x;
    for (; i < E; i += stride) atomicAdd(&deg[dst[i]], 1);
}

__global__ __launch_bounds__(1024) void scan_deg(const int* __restrict__ deg,
                                                 int* __restrict__ rowptr, int N) {
    __shared__ int part[1024];
    int t = threadIdx.x;
    int chunk = (N + 1023) / 1024;
    int b = t * chunk;
    int e = b + chunk;
    if (b > N) b = N;
    if (e > N) e = N;
    int s = 0;
    for (int i = b; i < e; ++i) s += deg[i];
    part[t] = s;
    __syncthreads();
    for (int off = 1; off < 1024; off <<= 1) {
        int v = (t >= off) ? part[t - off] : 0;
        __syncthreads();
        part[t] += v;
        __syncthreads();
    }
    int base = (t == 0) ? 0 : part[t - 1];
    for (int i = b; i < e; ++i) {
        rowptr[i] = base;
        base += deg[i];
    }
    if (t == 1023) rowptr[N] = base;
}

__global__ __launch_bounds__(256) void scatter_edges(const int* __restrict__ dst,
                                                     int* __restrict__ cursor,
                                                     int* __restrict__ eid, int E) {
    int i = blockIdx.x * blockDim.x + threadIdx.x;
    int stride = gridDim.x * blockDim.x;
    for (; i < E; i += stride) {
        int pos = atomicAdd(&cursor[dst[i]], 1);
        eid[pos] = i;
    }
}

// ---------------------------------------------------------------- gather (no atomics)
template <int IND>
__global__ __launch_bounds__(256) void gather_kernel(
    const int* __restrict__ rowptr, const int* __restrict__ eid, const int* __restrict__ src,
    const float* __restrict__ ea, const float* __restrict__ eW, const float* __restrict__ eb,
    const float* __restrict__ x, const float* __restrict__ epsp, float* __restrict__ agg, int N) {
    __shared__ __align__(16) float sW[12 * IND];
    __shared__ __align__(16) float sb[IND];
    int tid = threadIdx.x;
    for (int i = tid; i < 12 * IND; i += 256) sW[i] = eW[i];
    for (int i = tid; i < IND; i += 256) sb[i] = eb[i];
    __syncthreads();

    float onePlusEps = 1.0f + *epsp;
    int lane = tid & 31;
    int n = blockIdx.x * 8 + (tid >> 5);
    if (n >= N) return;
    int beg = rowptr[n], end = rowptr[n + 1];

    if constexpr (IND == 128) {
        int d0 = lane << 2;
        float4 acc = make_float4(0.f, 0.f, 0.f, 0.f);
        float4 bb = *(const float4*)&sb[d0];
        int i = beg;
        for (; i + 2 <= end; i += 2) {
            int e0 = eid[i], e1 = eid[i + 1];
            int s0 = src[e0], s1 = src[e1];
            float av0 = (lane < 12) ? ea[(size_t)e0 * 12 + lane] : 0.0f;
            float av1 = (lane < 12) ? ea[(size_t)e1 * 12 + lane] : 0.0f;
            float4 x0 = *(const float4*)&x[(size_t)s0 * 128 + d0];
            float4 x1 = *(const float4*)&x[(size_t)s1 * 128 + d0];
            float4 p0 = bb, p1 = bb;
#pragma unroll
            for (int k = 0; k < 12; ++k) {
                float a0 = __shfl(av0, k, 32);
                float a1 = __shfl(av1, k, 32);
                float4 w = *(const float4*)&sW[k * 128 + d0];
                p0.x = fmaf(a0, w.x, p0.x); p0.y = fmaf(a0, w.y, p0.y);
                p0.z = fmaf(a0, w.z, p0.z); p0.w = fmaf(a0, w.w, p0.w);
                p1.x = fmaf(a1, w.x, p1.x); p1.y = fmaf(a1, w.y, p1.y);
                p1.z = fmaf(a1, w.z, p1.z); p1.w = fmaf(a1, w.w, p1.w);
            }
            acc.x += fmaxf(x0.x + p0.x, 0.f) + fmaxf(x1.x + p1.x, 0.f);
            acc.y += fmaxf(x0.y + p0.y, 0.f) + fmaxf(x1.y + p1.y, 0.f);
            acc.z += fmaxf(x0.z + p0.z, 0.f) + fmaxf(x1.z + p1.z, 0.f);
            acc.w += fmaxf(x0.w + p0.w, 0.f) + fmaxf(x1.w + p1.w, 0.f);
        }
        if (i < end) {
            int e = eid[i];
            int s = src[e];
            float av = (lane < 12) ? ea[(size_t)e * 12 + lane] : 0.0f;
            float4 p = bb;
#pragma unroll
            for (int k = 0; k < 12; ++k) {
                float ak = __shfl(av, k, 32);
                float4 w = *(const float4*)&sW[k * 128 + d0];
                p.x = fmaf(ak, w.x, p.x); p.y = fmaf(ak, w.y, p.y);
                p.z = fmaf(ak, w.z, p.z); p.w = fmaf(ak, w.w, p.w);
            }
            float4 xv = *(const float4*)&x[(size_t)s * 128 + d0];
            acc.x += fmaxf(xv.x + p.x, 0.f);
            acc.y += fmaxf(xv.y + p.y, 0.f);
            acc.z += fmaxf(xv.z + p.z, 0.f);
            acc.w += fmaxf(xv.w + p.w, 0.f);
        }
        float4 xn = *(const float4*)&x[(size_t)n * 128 + d0];
        float4 o;
        o.x = fmaf(onePlusEps, xn.x, acc.x);
        o.y = fmaf(onePlusEps, xn.y, acc.y);
        o.z = fmaf(onePlusEps, xn.z, acc.z);
        o.w = fmaf(onePlusEps, xn.w, acc.w);
        *(float4*)&agg[(size_t)n * 128 + d0] = o;
    } else {
        int d = lane;
        float acc = 0.0f;
        float bb = (d < IND) ? sb[d] : 0.0f;
        for (int i = beg; i < end; ++i) {
            int e = eid[i];
            int s = src[e];
            float av = (lane < 12) ? ea[(size_t)e * 12 + lane] : 0.0f;
            float p = bb;
#pragma unroll
            for (int k = 0; k < 12; ++k) {
                float ak = __shfl(av, k, 32);
                if (d < IND) p = fmaf(ak, sW[k * IND + d], p);
            }
            if (d < IND) acc += fmaxf(x[(size_t)s * IND + d] + p, 0.0f);
        }
        if (d < IND) agg[(size_t)n * IND + d] = fmaf(onePlusEps, x[(size_t)n * IND + d], acc);
    }
}

// ---------------------------------------------------------------- W repack to MFMA frag order
// Wp[((t*kg + g)*64 + lane)*8 + j] = W[g*32 + (lane>>4)*8 + j][t*16 + (lane&15)], hi/lo planes.
__global__ __launch_bounds__(256) void repack_w(const float* __restrict__ W, int K, int N,
                                                ushort* __restrict__ hi, ushort* __restrict__ lo) {
    int kg = (K + 31) / 32;
    int total = (N / 16) * kg * 64;
    int idx = blockIdx.x * 256 + threadIdx.x;
    if (idx >= total) return;
    int l = idx & 63;
    int g = (idx >> 6) % kg;
    int t = (idx >> 6) / kg;
#pragma unroll
    for (int j = 0; j < 8; ++j) {
        int k = g * 32 + ((l >> 4) << 3) + j;
        int n = (t << 4) + (l & 15);
        float v = (k < K) ? W[(size_t)k * N + n] : 0.0f;
        ushort h = f2bf(v);
        hi[(size_t)idx * 8 + j] = h;
        lo[(size_t)idx * 8 + j] = f2bf(v - bf2f(h));
    }
}

// ---------------------------------------------------------------- MFMA GEMM (split-bf16)
// C[M,ldc] = pre(A[M,K]) @ W[K,Ncols] + bias, stats fused. BM=128 BN=64 BK=32, 4 waves 2x2.
template <bool PRE_BN>
__global__ __launch_bounds__(256) void mfma_gemm(const float* __restrict__ A, int M, int K,
                                                 const ushort* __restrict__ Wph,
                                                 const ushort* __restrict__ Wpl,
                                                 const float* __restrict__ bias,
                                                 const float* __restrict__ scale,
                                                 const float* __restrict__ shift,
                                                 float* __restrict__ C, int ldc,
                                                 float* __restrict__ sums,
                                                 float* __restrict__ sumsq) {
    __shared__ __align__(16) ushort As_hi[128 * 32];
    __shared__ __align__(16) ushort As_lo[128 * 32];
    int tid = threadIdx.x;
    int lane = tid & 63;
    int wv = tid >> 6;
    int wm = wv >> 1, wn = wv & 1;
    int row0 = blockIdx.x * 128;
    int col0 = blockIdx.y * 64;
    int kg = (K + 31) >> 5;

    f32x4 acc[4][2] = {};

    for (int g = 0; g < kg; ++g) {
        int k0 = g << 5;
        // stage A tile (128 x 32) as hi/lo bf16; rows contiguous (64B) -> conflict-free frags
        for (int c = tid; c < 1024; c += 256) {
            int row = c >> 3;
            int kc = (c & 7) << 2;
            int gm = row0 + row;
            float v[4] = {0.f, 0.f, 0.f, 0.f};
            if (gm < M) {
                const float* ap = &A[(size_t)gm * K + k0 + kc];
                if (k0 + kc + 4 <= K) {
                    float4 t4 = *(const float4*)ap;
                    v[0] = t4.x; v[1] = t4.y; v[2] = t4.z; v[3] = t4.w;
                } else {
#pragma unroll
                    for (int t = 0; t < 4; ++t)
                        if (k0 + kc + t < K) v[t] = ap[t];
                }
                if (PRE_BN) {
#pragma unroll
                    for (int t = 0; t < 4; ++t) {
                        int k = k0 + kc + t;
                        if (k < K) v[t] = fmaxf(fmaf(v[t], scale[k], shift[k]), 0.0f);
                    }
                }
            }
            ushort h[4], l2[4];
#pragma unroll
            for (int t = 0; t < 4; ++t) {
                h[t] = f2bf(v[t]);
                l2[t] = f2bf(v[t] - bf2f(h[t]));
            }
            int e = row * 32 + kc;
            *(ushort4*)&As_hi[e] = make_ushort4(h[0], h[1], h[2], h[3]);
            *(ushort4*)&As_lo[e] = make_ushort4(l2[0], l2[1], l2[2], l2[3]);
        }
        __syncthreads();

        bf16x8 bh[2], bl[2], ah[4], al[4];
#pragma unroll
        for (int nf = 0; nf < 2; ++nf) {
            int tn = (col0 >> 4) + (wn << 1) + nf;
            size_t off = (((size_t)tn * kg + g) * 64 + lane) * 8;
            bh[nf] = *(const bf16x8*)(Wph + off);
            bl[nf] = *(const bf16x8*)(Wpl + off);
        }
#pragma unroll
        for (int mf = 0; mf < 4; ++mf) {
            int e = ((wm << 6) + (mf << 4) + (lane & 15)) * 32 + ((lane >> 4) << 3);
            ah[mf] = *(const bf16x8*)&As_hi[e];
            al[mf] = *(const bf16x8*)&As_lo[e];
        }
#pragma unroll
        for (int mf = 0; mf < 4; ++mf)
#pragma unroll
            for (int nf = 0; nf < 2; ++nf) {
                acc[mf][nf] =
                    __builtin_amdgcn_mfma_f32_16x16x32_bf16(ah[mf], bh[nf], acc[mf][nf], 0, 0, 0);
                acc[mf][nf] =
                    __builtin_amdgcn_mfma_f32_16x16x32_bf16(ah[mf], bl[nf], acc[mf][nf], 0, 0, 0);
                acc[mf][nf] =
                    __builtin_amdgcn_mfma_f32_16x16x32_bf16(al[mf], bh[nf], acc[mf][nf], 0, 0, 0);
            }
        __syncthreads();
    }

    // epilogue: bias add, store, fused column stats (D: col=lane&15, row=(lane>>4)*4+q)
#pragma unroll
    for (int nf = 0; nf < 2; ++nf) {
        int col = col0 + (wn << 5) + (nf << 4) + (lane & 15);
        float bv = bias[col];
        float s = 0.f, qs = 0.f;
#pragma unroll
        for (int mf = 0; mf < 4; ++mf) {
            int rbase = row0 + (wm << 6) + (mf << 4) + ((lane >> 4) << 2);
#pragma unroll
            for (int q = 0; q < 4; ++q) {
                int row = rbase + q;
                if (row < M) {
                    float v = acc[mf][nf][q] + bv;
                    C[(size_t)row * ldc + col] = v;
                    s += v;
                    qs = fmaf(v, v, qs);
                }
            }
        }
        s += __shfl_xor(s, 16);
        s += __shfl_xor(s, 32);
        qs += __shfl_xor(qs, 16);
        qs += __shfl_xor(qs, 32);
        if (lane < 16) {
            atomicAdd(&sums[col], s);
            atomicAdd(&sumsq[col], qs);
        }
    }
}

// ---------------------------------------------------------------- BN finalize / apply
__global__ void finalize_bn(const float* __restrict__ sums, const float* __restrict__ sumsq,
                            const float* __restrict__ g, const float* __restrict__ b,
                            float* __restrict__ scale, float* __restrict__ shift, int C,
                            float invN) {
    int c = blockIdx.x * blockDim.x + threadIdx.x;
    if (c < C) {
        float mu = sums[c] * invN;
        float var = sumsq[c] * invN - mu * mu;
        float inv = rsqrtf(var + 1e-5f);
        float sc = g[c] * inv;
        scale[c] = sc;
        shift[c] = b[c] - mu * sc;
    }
}

template <bool RES>
__global__ __launch_bounds__(256) void bn_apply(const float* __restrict__ h,
                                                const float* __restrict__ scale,
                                                const float* __restrict__ shift,
                                                const float* __restrict__ xprev,
                                                float* __restrict__ out, int total4) {
    int i = blockIdx.x * blockDim.x + threadIdx.x;
    int stride = gridDim.x * blockDim.x;
    for (; i < total4; i += stride) {
        int c0 = (i & 31) << 2;
        float4 v = ((const float4*)h)[i];
        float4 o;
        o.x = fmaxf(fmaf(v.x, scale[c0 + 0], shift[c0 + 0]), 0.0f);
        o.y = fmaxf(fmaf(v.y, scale[c0 + 1], shift[c0 + 1]), 0.0f);
        o.z = fmaxf(fmaf(v.z, scale[c0 + 2], shift[c0 + 2]), 0.0f);
        o.w = fmaxf(fmaf(v.w, scale[c0 + 3], shift[c0 + 3]), 0.0f);
        if (RES) {
            float4 xp = ((const float4*)xprev)[i];
            o.x = fmaf(0.3f, o.x, xp.x);
            o.y = fmaf(0.3f, o.y, xp.y);
            o.z = fmaf(0.3f, o.z, xp.z);
            o.w = fmaf(0.3f, o.w, xp.w);
        }
        ((float4*)out)[i] = o;
    }
}

// ---------------------------------------------------------------- launch
extern "C" void kernel_launch(void* const* d_in, const int* in_sizes, int n_in, void* d_out,
                              int out_size, void* d_ws, size_t ws_size, hipStream_t stream) {
    const float* x_in = (const float*)d_in[0];
    const int* ei = (const int*)d_in[1];
    const float* ea = (const float*)d_in[2];
    const int IN_DIM = 27;
    const int H = 128;
    int N = in_sizes[0] / IN_DIM;
    int E = in_sizes[1] / 2;
    const int* src = ei;
    const int* dst = ei + E;

    auto L = [&](int layer, int j) -> const float* {
        return (const float*)d_in[3 + 11 * layer + j];
    };
    // j: 0 eps, 1 eW, 2 eb, 3 W1, 4 b1, 5 g1, 6 be1, 7 W2, 8 b2, 9 ng, 10 nb

    float* X0 = (float*)d_ws;         // [N,128]
    float* AGG = X0 + (size_t)N * H;  // [N,128] (also h2)
    float* H1 = AGG + (size_t)N * H;  // [N,256]
    float* STATS = H1 + (size_t)N * 2 * H;
    float* sums1 = STATS;
    float* sq1 = STATS + 256;
    float* sums2 = STATS + 512;
    float* sq2 = STATS + 640;
    float* scale1 = STATS + 768;
    float* shift1 = STATS + 1024;
    float* scale2 = STATS + 1280;
    float* shift2 = STATS + 1408;
    int* rowptr = (int*)(STATS + 1536);  // N+1
    int* cursor = rowptr + (N + 1);      // N
    int* eid = cursor + N;               // E
    // Wp buffers, 16B aligned, after eid
    size_t wp_off = ((size_t)(eid + E - (int*)d_ws) * 4 + 15) & ~(size_t)15;
    ushort* Wp1h = (ushort*)((char*)d_ws + wp_off);  // 32768 each
    ushort* Wp1l = Wp1h + 32768;
    ushort* Wp2h = Wp1l + 32768;
    ushort* Wp2l = Wp2h + 32768;
    float* X1 = (float*)d_out;

    float invN = 1.0f / (float)N;
    int gridM = cdiv(N, 128);
    int gatherG = cdiv(N, 8);

    // ---- CSR build (once)
    hipMemsetAsync(rowptr, 0, (size_t)(N + 1) * sizeof(int), stream);
    histogram_dst<<<1024, 256, 0, stream>>>(dst, rowptr, E);
    scan_deg<<<1, 1024, 0, stream>>>(rowptr, cursor, N);
    hipMemcpyAsync(rowptr, cursor, (size_t)(N + 1) * sizeof(int), hipMemcpyDeviceToDevice, stream);
    scatter_edges<<<1024, 256, 0, stream>>>(dst, cursor, eid, E);

    for (int i = 0; i < 3; ++i) {
        int ind = (i == 0) ? IN_DIM : H;
        const float* xin = (i == 0) ? x_in : ((i == 1) ? X0 : X1);
        float* xout = (i == 2) ? (float*)d_out : ((i == 0) ? X0 : X1);

        hipMemsetAsync(STATS, 0, 768 * sizeof(float), stream);

        int kg1 = cdiv(ind, 32);
        int tot1 = 16 * kg1 * 64;  // Ncols=256
        repack_w<<<cdiv(tot1, 256), 256, 0, stream>>>(L(i, 3), ind, 256, Wp1h, Wp1l);
        int tot2 = 8 * 8 * 64;  // K=256 kg=8, Ncols=128
        repack_w<<<cdiv(tot2, 256), 256, 0, stream>>>(L(i, 7), 256, 128, Wp2h, Wp2l);

        if (i == 0)
            gather_kernel<27><<<gatherG, 256, 0, stream>>>(rowptr, eid, src, ea, L(i, 1), L(i, 2),
                                                           xin, L(i, 0), AGG, N);
        else
            gather_kernel<128><<<gatherG, 256, 0, stream>>>(rowptr, eid, src, ea, L(i, 1), L(i, 2),
                                                            xin, L(i, 0), AGG, N);

        // h1 = agg @ W1 + b1   [N,256], stats fused
        mfma_gemm<false><<<dim3(gridM, 4), 256, 0, stream>>>(AGG, N, ind, Wp1h, Wp1l, L(i, 4),
                                                             nullptr, nullptr, H1, 256, sums1, sq1);
        finalize_bn<<<1, 256, 0, stream>>>(sums1, sq1, L(i, 5), L(i, 6), scale1, shift1, 256, invN);

        // h2 = relu(bn1(h1)) @ W2 + b2   [N,128], stats fused
        mfma_gemm<true><<<dim3(gridM, 2), 256, 0, stream>>>(H1, N, 256, Wp2h, Wp2l, L(i, 8),
                                                            scale1, shift1, AGG, 128, sums2, sq2);
        finalize_bn<<<1, 256, 0, stream>>>(sums2, sq2, L(i, 9), L(i, 10), scale2, shift2, 128,
                                           invN);

        int total4 = N * H / 4;
        if (i == 1)
            bn_apply<true><<<2048, 256, 0, stream>>>(AGG, scale2, shift2, X0, xout, total4);
        else
            bn_apply<false><<<2048, 256, 0, stream>>>(AGG, scale2, shift2, nullptr, xout, total4);
    }
}

// Round 6
// 821.075 us; speedup vs baseline: 3.3324x; 1.1784x over previous
//
#include <hip/hip_runtime.h>
#include <hip/hip_bf16.h>

// GINE backbone, 3 layers. N=50000, E=500000, IN=27, ED=12, H=128.
// Round 5 -> 6: gathers restructured for 4-edge ILP (both IND variants);
// GEMMs widened to full-N tiles (512 threads, grid-y=1) to kill redundant
// A staging (was 4x/2x re-read of AGG/H1).

typedef __attribute__((ext_vector_type(8))) short bf16x8;
typedef __attribute__((ext_vector_type(4))) float f32x4;

static inline int cdiv(int a, int b) { return (a + b - 1) / b; }

__device__ inline ushort f2bf(float f) {
    uint32_t u = __float_as_uint(f);
    return (ushort)((u + 0x7FFFu + ((u >> 16) & 1u)) >> 16);
}
__device__ inline float bf2f(ushort h) { return __uint_as_float(((uint32_t)h) << 16); }

// ---------------------------------------------------------------- CSR build
__global__ __launch_bounds__(256) void histogram_dst(const int* __restrict__ dst,
                                                     int* __restrict__ deg, int E) {
    int i = blockIdx.x * blockDim.x + threadIdx.x;
    int stride = gridDim.x * blockDim.x;
    for (; i < E; i += stride) atomicAdd(&deg[dst[i]], 1);
}

__global__ __launch_bounds__(1024) void scan_deg(const int* __restrict__ deg,
                                                 int* __restrict__ rowptr, int N) {
    __shared__ int part[1024];
    int t = threadIdx.x;
    int chunk = (N + 1023) / 1024;
    int b = t * chunk;
    int e = b + chunk;
    if (b > N) b = N;
    if (e > N) e = N;
    int s = 0;
    for (int i = b; i < e; ++i) s += deg[i];
    part[t] = s;
    __syncthreads();
    for (int off = 1; off < 1024; off <<= 1) {
        int v = (t >= off) ? part[t - off] : 0;
        __syncthreads();
        part[t] += v;
        __syncthreads();
    }
    int base = (t == 0) ? 0 : part[t - 1];
    for (int i = b; i < e; ++i) {
        rowptr[i] = base;
        base += deg[i];
    }
    if (t == 1023) rowptr[N] = base;
}

__global__ __launch_bounds__(256) void scatter_edges(const int* __restrict__ dst,
                                                     int* __restrict__ cursor,
                                                     int* __restrict__ eid, int E) {
    int i = blockIdx.x * blockDim.x + threadIdx.x;
    int stride = gridDim.x * blockDim.x;
    for (; i < E; i += stride) {
        int pos = atomicAdd(&cursor[dst[i]], 1);
        eid[pos] = i;
    }
}

// ---------------------------------------------------------------- gather IND=128
// 32 lanes per node, 4 dims/lane (float4), 4 edges in flight.
__global__ __launch_bounds__(256) void gather128(
    const int* __restrict__ rowptr, const int* __restrict__ eid, const int* __restrict__ src,
    const float* __restrict__ ea, const float* __restrict__ eW, const float* __restrict__ eb,
    const float* __restrict__ x, const float* __restrict__ epsp, float* __restrict__ agg, int N) {
    __shared__ __align__(16) float sW[12 * 128];
    __shared__ __align__(16) float sb[128];
    int tid = threadIdx.x;
    for (int i = tid; i < 12 * 128; i += 256) sW[i] = eW[i];
    if (tid < 128) sb[tid] = eb[tid];
    __syncthreads();

    float onePlusEps = 1.0f + *epsp;
    int lane = tid & 31;
    int n = blockIdx.x * 8 + (tid >> 5);
    if (n >= N) return;
    int beg = rowptr[n], end = rowptr[n + 1];
    int d0 = lane << 2;
    float4 bb = *(const float4*)&sb[d0];
    float4 acc = make_float4(0.f, 0.f, 0.f, 0.f);

    int i = beg;
    for (; i + 4 <= end; i += 4) {
        int e[4], s[4];
        float av[4];
        float4 xv[4], p[4];
#pragma unroll
        for (int j = 0; j < 4; ++j) e[j] = eid[i + j];
#pragma unroll
        for (int j = 0; j < 4; ++j) {
            s[j] = src[e[j]];
            av[j] = (lane < 12) ? ea[(size_t)e[j] * 12 + lane] : 0.0f;
        }
#pragma unroll
        for (int j = 0; j < 4; ++j) {
            xv[j] = *(const float4*)&x[(size_t)s[j] * 128 + d0];
            p[j] = bb;
        }
#pragma unroll
        for (int k = 0; k < 12; ++k) {
            float4 w = *(const float4*)&sW[k * 128 + d0];
#pragma unroll
            for (int j = 0; j < 4; ++j) {
                float a = __shfl(av[j], k, 32);
                p[j].x = fmaf(a, w.x, p[j].x);
                p[j].y = fmaf(a, w.y, p[j].y);
                p[j].z = fmaf(a, w.z, p[j].z);
                p[j].w = fmaf(a, w.w, p[j].w);
            }
        }
#pragma unroll
        for (int j = 0; j < 4; ++j) {
            acc.x += fmaxf(xv[j].x + p[j].x, 0.f);
            acc.y += fmaxf(xv[j].y + p[j].y, 0.f);
            acc.z += fmaxf(xv[j].z + p[j].z, 0.f);
            acc.w += fmaxf(xv[j].w + p[j].w, 0.f);
        }
    }
    for (; i < end; ++i) {
        int e = eid[i];
        int s = src[e];
        float av = (lane < 12) ? ea[(size_t)e * 12 + lane] : 0.0f;
        float4 p = bb;
#pragma unroll
        for (int k = 0; k < 12; ++k) {
            float ak = __shfl(av, k, 32);
            float4 w = *(const float4*)&sW[k * 128 + d0];
            p.x = fmaf(ak, w.x, p.x);
            p.y = fmaf(ak, w.y, p.y);
            p.z = fmaf(ak, w.z, p.z);
            p.w = fmaf(ak, w.w, p.w);
        }
        float4 xv = *(const float4*)&x[(size_t)s * 128 + d0];
        acc.x += fmaxf(xv.x + p.x, 0.f);
        acc.y += fmaxf(xv.y + p.y, 0.f);
        acc.z += fmaxf(xv.z + p.z, 0.f);
        acc.w += fmaxf(xv.w + p.w, 0.f);
    }
    float4 xn = *(const float4*)&x[(size_t)n * 128 + d0];
    float4 o;
    o.x = fmaf(onePlusEps, xn.x, acc.x);
    o.y = fmaf(onePlusEps, xn.y, acc.y);
    o.z = fmaf(onePlusEps, xn.z, acc.z);
    o.w = fmaf(onePlusEps, xn.w, acc.w);
    *(float4*)&agg[(size_t)n * 128 + d0] = o;
}

// ---------------------------------------------------------------- gather IND=27
// 32 lanes per node = 4 sub-groups of 8 lanes; each sub owns one edge
// (4 edges in flight); lane sl covers dims [4*sl, 4*sl+4) (sl<7).
__global__ __launch_bounds__(256) void gather27(
    const int* __restrict__ rowptr, const int* __restrict__ eid, const int* __restrict__ src,
    const float* __restrict__ ea, const float* __restrict__ eW, const float* __restrict__ eb,
    const float* __restrict__ x, const float* __restrict__ epsp, float* __restrict__ agg, int N) {
    __shared__ __align__(16) float sW[12 * 28 + 4];  // padded cols (27 -> 28)
    __shared__ __align__(16) float sb[32];
    int tid = threadIdx.x;
    for (int i = tid; i < 12 * 28 + 4; i += 256) sW[i] = 0.0f;
    if (tid < 32) sb[tid] = 0.0f;
    __syncthreads();
    for (int i = tid; i < 12 * 27; i += 256) {
        int k = i / 27, d = i - k * 27;
        sW[k * 28 + d] = eW[i];
    }
    if (tid < 27) sb[tid] = eb[tid];
    __syncthreads();

    float onePlusEps = 1.0f + *epsp;
    int lane = tid & 31;
    int n = blockIdx.x * 8 + (tid >> 5);
    if (n >= N) return;
    int beg = rowptr[n], end = rowptr[n + 1];
    int sub = lane >> 3, sl = lane & 7;
    int d0 = sl << 2;          // 0..28
    int d0c = (sl < 7) ? d0 : 24;  // clamp for LDS reads (sl==7 unused)
    float4 bb = *(const float4*)&sb[d0c];
    float4 acc = make_float4(0.f, 0.f, 0.f, 0.f);

    int iters = (end - beg + 3) >> 2;
    for (int it = 0; it < iters; ++it) {
        int i = beg + it * 4 + sub;
        bool v = i < end;  // uniform within the 8-lane sub
        int e = v ? eid[i] : 0;
        int s = v ? src[e] : 0;
        float avA = v ? ea[(size_t)e * 12 + sl] : 0.0f;
        float avB = (v && sl < 4) ? ea[(size_t)e * 12 + 8 + sl] : 0.0f;
        float4 xv = make_float4(0.f, 0.f, 0.f, 0.f);
        if (v) {
            if (sl < 6) {
                xv = *(const float4*)&x[(size_t)s * 27 + d0];
            } else if (sl == 6) {
                xv.x = x[(size_t)s * 27 + 24];
                xv.y = x[(size_t)s * 27 + 25];
                xv.z = x[(size_t)s * 27 + 26];
            }
        }
        float4 p = bb;
#pragma unroll
        for (int k = 0; k < 8; ++k) {
            float ak = __shfl(avA, k, 8);
            float4 w = *(const float4*)&sW[k * 28 + d0c];
            p.x = fmaf(ak, w.x, p.x);
            p.y = fmaf(ak, w.y, p.y);
            p.z = fmaf(ak, w.z, p.z);
            p.w = fmaf(ak, w.w, p.w);
        }
#pragma unroll
        for (int k = 8; k < 12; ++k) {
            float ak = __shfl(avB, k - 8, 8);
            float4 w = *(const float4*)&sW[k * 28 + d0c];
            p.x = fmaf(ak, w.x, p.x);
            p.y = fmaf(ak, w.y, p.y);
            p.z = fmaf(ak, w.z, p.z);
            p.w = fmaf(ak, w.w, p.w);
        }
        if (v) {
            acc.x += fmaxf(xv.x + p.x, 0.f);
            acc.y += fmaxf(xv.y + p.y, 0.f);
            acc.z += fmaxf(xv.z + p.z, 0.f);
            acc.w += fmaxf(xv.w + p.w, 0.f);
        }
    }
    // combine the 4 sub-groups (same sl across subs = same dims)
    acc.x += __shfl_xor(acc.x, 8, 32);
    acc.y += __shfl_xor(acc.y, 8, 32);
    acc.z += __shfl_xor(acc.z, 8, 32);
    acc.w += __shfl_xor(acc.w, 8, 32);
    acc.x += __shfl_xor(acc.x, 16, 32);
    acc.y += __shfl_xor(acc.y, 16, 32);
    acc.z += __shfl_xor(acc.z, 16, 32);
    acc.w += __shfl_xor(acc.w, 16, 32);

    if (sub == 0) {
        if (sl < 6) {
            float4 xn = *(const float4*)&x[(size_t)n * 27 + d0];
            float4 o;
            o.x = fmaf(onePlusEps, xn.x, acc.x);
            o.y = fmaf(onePlusEps, xn.y, acc.y);
            o.z = fmaf(onePlusEps, xn.z, acc.z);
            o.w = fmaf(onePlusEps, xn.w, acc.w);
            *(float4*)&agg[(size_t)n * 27 + d0] = o;
        } else if (sl == 6) {
            agg[(size_t)n * 27 + 24] = fmaf(onePlusEps, x[(size_t)n * 27 + 24], acc.x);
            agg[(size_t)n * 27 + 25] = fmaf(onePlusEps, x[(size_t)n * 27 + 25], acc.y);
            agg[(size_t)n * 27 + 26] = fmaf(onePlusEps, x[(size_t)n * 27 + 26], acc.z);
        }
    }
}

// ---------------------------------------------------------------- W repack to MFMA frag order
// Wp[((t*kg + g)*64 + lane)*8 + j] = W[g*32 + (lane>>4)*8 + j][t*16 + (lane&15)], hi/lo planes.
__global__ __launch_bounds__(256) void repack_w(const float* __restrict__ W, int K, int N,
                                                ushort* __restrict__ hi, ushort* __restrict__ lo) {
    int kg = (K + 31) / 32;
    int total = (N / 16) * kg * 64;
    int idx = blockIdx.x * 256 + threadIdx.x;
    if (idx >= total) return;
    int l = idx & 63;
    int g = (idx >> 6) % kg;
    int t = (idx >> 6) / kg;
#pragma unroll
    for (int j = 0; j < 8; ++j) {
        int k = g * 32 + ((l >> 4) << 3) + j;
        int n = (t << 4) + (l & 15);
        float v = (k < K) ? W[(size_t)k * N + n] : 0.0f;
        ushort h = f2bf(v);
        hi[(size_t)idx * 8 + j] = h;
        lo[(size_t)idx * 8 + j] = f2bf(v - bf2f(h));
    }
}

// ---------------------------------------------------------------- MFMA GEMM (split-bf16)
// C[M, 64*NF] = pre(A[M,K]) @ W + bias, stats fused.
// BM=128, BN=64*NF (full width, grid-y=1), 512 thr = 8 waves (2 row x 4 col).
template <int NF, bool PRE_BN>
__global__ __launch_bounds__(512) void mfma_gemm(const float* __restrict__ A, int M, int K,
                                                 const ushort* __restrict__ Wph,
                                                 const ushort* __restrict__ Wpl,
                                                 const float* __restrict__ bias,
                                                 const float* __restrict__ scale,
                                                 const float* __restrict__ shift,
                                                 float* __restrict__ C, int ldc,
                                                 float* __restrict__ sums,
                                                 float* __restrict__ sumsq) {
    __shared__ __align__(16) ushort As_hi[128 * 32];
    __shared__ __align__(16) ushort As_lo[128 * 32];
    int tid = threadIdx.x;
    int lane = tid & 63;
    int wv = tid >> 6;
    int wm = wv >> 2, wn = wv & 3;
    int row0 = blockIdx.x * 128;
    int kg = (K + 31) >> 5;

    f32x4 acc[4][NF] = {};

    for (int g = 0; g < kg; ++g) {
        int k0 = g << 5;
        // stage A tile (128 x 32) as hi/lo bf16
        for (int c = tid; c < 1024; c += 512) {
            int row = c >> 3;
            int kc = (c & 7) << 2;
            int gm = row0 + row;
            float v[4] = {0.f, 0.f, 0.f, 0.f};
            if (gm < M) {
                const float* ap = &A[(size_t)gm * K + k0 + kc];
                if (k0 + kc + 4 <= K) {
                    float4 t4 = *(const float4*)ap;
                    v[0] = t4.x; v[1] = t4.y; v[2] = t4.z; v[3] = t4.w;
                } else {
#pragma unroll
                    for (int t = 0; t < 4; ++t)
                        if (k0 + kc + t < K) v[t] = ap[t];
                }
                if (PRE_BN) {
#pragma unroll
                    for (int t = 0; t < 4; ++t) {
                        int k = k0 + kc + t;
                        if (k < K) v[t] = fmaxf(fmaf(v[t], scale[k], shift[k]), 0.0f);
                    }
                }
            }
            ushort h[4], l2[4];
#pragma unroll
            for (int t = 0; t < 4; ++t) {
                h[t] = f2bf(v[t]);
                l2[t] = f2bf(v[t] - bf2f(h[t]));
            }
            int e = row * 32 + kc;
            *(ushort4*)&As_hi[e] = make_ushort4(h[0], h[1], h[2], h[3]);
            *(ushort4*)&As_lo[e] = make_ushort4(l2[0], l2[1], l2[2], l2[3]);
        }
        __syncthreads();

        bf16x8 ah[4], al[4];
#pragma unroll
        for (int mf = 0; mf < 4; ++mf) {
            int e = ((wm << 6) + (mf << 4) + (lane & 15)) * 32 + ((lane >> 4) << 3);
            ah[mf] = *(const bf16x8*)&As_hi[e];
            al[mf] = *(const bf16x8*)&As_lo[e];
        }
#pragma unroll
        for (int nf = 0; nf < NF; ++nf) {
            int tn = wn * NF + nf;
            size_t off = (((size_t)tn * kg + g) * 64 + lane) * 8;
            bf16x8 bh = *(const bf16x8*)(Wph + off);
            bf16x8 bl = *(const bf16x8*)(Wpl + off);
#pragma unroll
            for (int mf = 0; mf < 4; ++mf) {
                acc[mf][nf] =
                    __builtin_amdgcn_mfma_f32_16x16x32_bf16(ah[mf], bh, acc[mf][nf], 0, 0, 0);
                acc[mf][nf] =
                    __builtin_amdgcn_mfma_f32_16x16x32_bf16(ah[mf], bl, acc[mf][nf], 0, 0, 0);
                acc[mf][nf] =
                    __builtin_amdgcn_mfma_f32_16x16x32_bf16(al[mf], bh, acc[mf][nf], 0, 0, 0);
            }
        }
        __syncthreads();
    }

    // epilogue: bias add, store, fused column stats (D: col=lane&15, row=(lane>>4)*4+q)
#pragma unroll
    for (int nf = 0; nf < NF; ++nf) {
        int col = (wn * NF + nf) * 16 + (lane & 15);
        float bv = bias[col];
        float s = 0.f, qs = 0.f;
#pragma unroll
        for (int mf = 0; mf < 4; ++mf) {
            int rbase = row0 + (wm << 6) + (mf << 4) + ((lane >> 4) << 2);
#pragma unroll
            for (int q = 0; q < 4; ++q) {
                int row = rbase + q;
                if (row < M) {
                    float v = acc[mf][nf][q] + bv;
                    C[(size_t)row * ldc + col] = v;
                    s += v;
                    qs = fmaf(v, v, qs);
                }
            }
        }
        s += __shfl_xor(s, 16);
        s += __shfl_xor(s, 32);
        qs += __shfl_xor(qs, 16);
        qs += __shfl_xor(qs, 32);
        if (lane < 16) {
            atomicAdd(&sums[col], s);
            atomicAdd(&sumsq[col], qs);
        }
    }
}

// ---------------------------------------------------------------- BN finalize / apply
__global__ void finalize_bn(const float* __restrict__ sums, const float* __restrict__ sumsq,
                            const float* __restrict__ g, const float* __restrict__ b,
                            float* __restrict__ scale, float* __restrict__ shift, int C,
                            float invN) {
    int c = blockIdx.x * blockDim.x + threadIdx.x;
    if (c < C) {
        float mu = sums[c] * invN;
        float var = sumsq[c] * invN - mu * mu;
        float inv = rsqrtf(var + 1e-5f);
        float sc = g[c] * inv;
        scale[c] = sc;
        shift[c] = b[c] - mu * sc;
    }
}

template <bool RES>
__global__ __launch_bounds__(256) void bn_apply(const float* __restrict__ h,
                                                const float* __restrict__ scale,
                                                const float* __restrict__ shift,
                                                const float* __restrict__ xprev,
                                                float* __restrict__ out, int total4) {
    int i = blockIdx.x * blockDim.x + threadIdx.x;
    int stride = gridDim.x * blockDim.x;
    for (; i < total4; i += stride) {
        int c0 = (i & 31) << 2;
        float4 v = ((const float4*)h)[i];
        float4 o;
        o.x = fmaxf(fmaf(v.x, scale[c0 + 0], shift[c0 + 0]), 0.0f);
        o.y = fmaxf(fmaf(v.y, scale[c0 + 1], shift[c0 + 1]), 0.0f);
        o.z = fmaxf(fmaf(v.z, scale[c0 + 2], shift[c0 + 2]), 0.0f);
        o.w = fmaxf(fmaf(v.w, scale[c0 + 3], shift[c0 + 3]), 0.0f);
        if (RES) {
            float4 xp = ((const float4*)xprev)[i];
            o.x = fmaf(0.3f, o.x, xp.x);
            o.y = fmaf(0.3f, o.y, xp.y);
            o.z = fmaf(0.3f, o.z, xp.z);
            o.w = fmaf(0.3f, o.w, xp.w);
        }
        ((float4*)out)[i] = o;
    }
}

// ---------------------------------------------------------------- launch
extern "C" void kernel_launch(void* const* d_in, const int* in_sizes, int n_in, void* d_out,
                              int out_size, void* d_ws, size_t ws_size, hipStream_t stream) {
    const float* x_in = (const float*)d_in[0];
    const int* ei = (const int*)d_in[1];
    const float* ea = (const float*)d_in[2];
    const int IN_DIM = 27;
    const int H = 128;
    int N = in_sizes[0] / IN_DIM;
    int E = in_sizes[1] / 2;
    const int* src = ei;
    const int* dst = ei + E;

    auto L = [&](int layer, int j) -> const float* {
        return (const float*)d_in[3 + 11 * layer + j];
    };
    // j: 0 eps, 1 eW, 2 eb, 3 W1, 4 b1, 5 g1, 6 be1, 7 W2, 8 b2, 9 ng, 10 nb

    float* X0 = (float*)d_ws;         // [N,128]
    float* AGG = X0 + (size_t)N * H;  // [N,128] (also h2)
    float* H1 = AGG + (size_t)N * H;  // [N,256]
    float* STATS = H1 + (size_t)N * 2 * H;
    float* sums1 = STATS;
    float* sq1 = STATS + 256;
    float* sums2 = STATS + 512;
    float* sq2 = STATS + 640;
    float* scale1 = STATS + 768;
    float* shift1 = STATS + 1024;
    float* scale2 = STATS + 1280;
    float* shift2 = STATS + 1408;
    int* rowptr = (int*)(STATS + 1536);  // N+1
    int* cursor = rowptr + (N + 1);      // N
    int* eid = cursor + N;               // E
    size_t wp_off = ((size_t)(eid + E - (int*)d_ws) * 4 + 15) & ~(size_t)15;
    ushort* Wp1h = (ushort*)((char*)d_ws + wp_off);  // 32768 each
    ushort* Wp1l = Wp1h + 32768;
    ushort* Wp2h = Wp1l + 32768;
    ushort* Wp2l = Wp2h + 32768;
    float* X1 = (float*)d_out;

    float invN = 1.0f / (float)N;
    int gridM = cdiv(N, 128);
    int gatherG = cdiv(N, 8);

    // ---- CSR build (once)
    hipMemsetAsync(rowptr, 0, (size_t)(N + 1) * sizeof(int), stream);
    histogram_dst<<<1024, 256, 0, stream>>>(dst, rowptr, E);
    scan_deg<<<1, 1024, 0, stream>>>(rowptr, cursor, N);
    hipMemcpyAsync(rowptr, cursor, (size_t)(N + 1) * sizeof(int), hipMemcpyDeviceToDevice, stream);
    scatter_edges<<<1024, 256, 0, stream>>>(dst, cursor, eid, E);

    for (int i = 0; i < 3; ++i) {
        int ind = (i == 0) ? IN_DIM : H;
        const float* xin = (i == 0) ? x_in : ((i == 1) ? X0 : X1);
        float* xout = (i == 2) ? (float*)d_out : ((i == 0) ? X0 : X1);

        hipMemsetAsync(STATS, 0, 768 * sizeof(float), stream);

        int kg1 = cdiv(ind, 32);
        int tot1 = 16 * kg1 * 64;  // Ncols=256
        repack_w<<<cdiv(tot1, 256), 256, 0, stream>>>(L(i, 3), ind, 256, Wp1h, Wp1l);
        int tot2 = 8 * 8 * 64;  // K=256 kg=8, Ncols=128
        repack_w<<<cdiv(tot2, 256), 256, 0, stream>>>(L(i, 7), 256, 128, Wp2h, Wp2l);

        if (i == 0)
            gather27<<<gatherG, 256, 0, stream>>>(rowptr, eid, src, ea, L(i, 1), L(i, 2), xin,
                                                  L(i, 0), AGG, N);
        else
            gather128<<<gatherG, 256, 0, stream>>>(rowptr, eid, src, ea, L(i, 1), L(i, 2), xin,
                                                   L(i, 0), AGG, N);

        // h1 = agg @ W1 + b1   [N,256], stats fused, full-width tile
        mfma_gemm<4, false><<<gridM, 512, 0, stream>>>(AGG, N, ind, Wp1h, Wp1l, L(i, 4), nullptr,
                                                       nullptr, H1, 256, sums1, sq1);
        finalize_bn<<<1, 256, 0, stream>>>(sums1, sq1, L(i, 5), L(i, 6), scale1, shift1, 256, invN);

        // h2 = relu(bn1(h1)) @ W2 + b2   [N,128], stats fused, full-width tile
        mfma_gemm<2, true><<<gridM, 512, 0, stream>>>(H1, N, 256, Wp2h, Wp2l, L(i, 8), scale1,
                                                      shift1, AGG, 128, sums2, sq2);
        finalize_bn<<<1, 256, 0, stream>>>(sums2, sq2, L(i, 9), L(i, 10), scale2, shift2, 128,
                                           invN);

        int total4 = N * H / 4;
        if (i == 1)
            bn_apply<true><<<2048, 256, 0, stream>>>(AGG, scale2, shift2, X0, xout, total4);
        else
            bn_apply<false><<<2048, 256, 0, stream>>>(AGG, scale2, shift2, nullptr, xout, total4);
    }
}